// Round 15
// baseline (481.308 us; speedup 1.0000x reference)
//
#include <hip/hip_runtime.h>
#include <stdint.h>

typedef __attribute__((ext_vector_type(4))) int i32x4;

#define EPSQ 1e-5f

__device__ __forceinline__ void async_copy16(const void* g, void* l) {
  __builtin_amdgcn_global_load_lds(
      (const __attribute__((address_space(1))) unsigned int*)g,
      (__attribute__((address_space(3))) unsigned int*)l,
      16, 0, 0);
}

// quantize 4 floats -> 4 packed int8 codes (two's complement)
__device__ __forceinline__ unsigned pack4_q(float x, float y, float z, float w,
                                            float scale, float lo, float hi) {
  int q0 = (int)fminf(fmaxf(rintf(x * scale), lo), hi);
  int q1 = (int)fminf(fmaxf(rintf(y * scale), lo), hi);
  int q2 = (int)fminf(fmaxf(rintf(z * scale), lo), hi);
  int q3 = (int)fminf(fmaxf(rintf(w * scale), lo), hi);
  return (unsigned)(q0 & 255) | ((unsigned)(q1 & 255) << 8) |
         ((unsigned)(q2 & 255) << 16) | ((unsigned)(q3 & 255) << 24);
}

// ---------------- W absmean reduction (double accumulation) ----------------
__global__ __launch_bounds__(256) void abssum_kernel(const float4* __restrict__ W,
                                                     double* __restrict__ sum, int n4) {
  __shared__ double red[4];
  double acc = 0.0;
  int stride = gridDim.x * blockDim.x;
  for (int v = blockIdx.x * blockDim.x + threadIdx.x; v < n4; v += stride) {
    float4 p = W[v];
    acc += (double)fabsf(p.x) + (double)fabsf(p.y) +
           (double)fabsf(p.z) + (double)fabsf(p.w);
  }
  for (int off = 32; off > 0; off >>= 1) acc += __shfl_down(acc, off);
  if ((threadIdx.x & 63) == 0) red[threadIdx.x >> 6] = acc;
  __syncthreads();
  if (threadIdx.x == 0)
    atomicAdd(sum, (red[0] + red[1]) + (red[2] + red[3]));
}

// ---------------- finalize scalars + A_eff ----------------
// scalf layout: [0..1]=double sum|W|, [2]=mw (dequant), [3]=sw=1/mw (quant)
__global__ void finalize_kernel(const float* __restrict__ A_raw, float* __restrict__ scalf,
                                float* __restrict__ a_eff, int D, double inv_cnt) {
  int i = blockIdx.x * blockDim.x + threadIdx.x;
  if (i < D) a_eff[i] = 0.99f * tanhf(A_raw[i]);
  if (i == 0) {
    double s = *(const double*)scalf;
    float mw = fmaxf((float)(s * inv_cnt), EPSQ);  // clip(mean|W|, EPS)
    scalf[2] = mw;
    scalf[3] = 1.0f / mw;
  }
}

// ---------------- ternary quantize W -> int8 codes {-1,0,1} ----------------
__global__ __launch_bounds__(256) void quantw_kernel(const float4* __restrict__ W,
                                                     unsigned* __restrict__ Wq,
                                                     const float* __restrict__ scalf, int n4) {
  float sw = scalf[3];
  int base = blockIdx.x * 1024 + threadIdx.x;
#pragma unroll
  for (int j = 0; j < 4; ++j) {
    int idx = base + 256 * j;
    if (idx < n4) {
      float4 p = W[idx];
      Wq[idx] = pack4_q(p.x, p.y, p.z, p.w, sw, -1.f, 1.f);
    }
  }
}

// ---------------- per-token int8 quant of e -> int8 codes [-127,127] -------
__global__ __launch_bounds__(256) void quante_kernel(const float* __restrict__ E,
                                                     char* __restrict__ Eq,
                                                     float* __restrict__ rowscale, int K) {
  int wave = threadIdx.x >> 6;
  int lane = threadIdx.x & 63;
  int row = blockIdx.x * 4 + wave;
  const float4* src = (const float4*)(E + (size_t)row * K);
  float4 v[8];  // K=2048: 512 float4/row = 64 lanes x 8
#pragma unroll
  for (int j = 0; j < 8; ++j) v[j] = src[lane + 64 * j];
  float amax = 0.f;
#pragma unroll
  for (int j = 0; j < 8; ++j)
    amax = fmaxf(amax, fmaxf(fmaxf(fabsf(v[j].x), fabsf(v[j].y)),
                             fmaxf(fabsf(v[j].z), fabsf(v[j].w))));
#pragma unroll
  for (int off = 32; off > 0; off >>= 1) amax = fmaxf(amax, __shfl_xor(amax, off));
  float clipped = fmaxf(amax, EPSQ);
  float scale = 127.0f / clipped;  // matches jax: 127/clip(max|x|,EPS)
  unsigned* dst = (unsigned*)(Eq + (size_t)row * K);
#pragma unroll
  for (int j = 0; j < 8; ++j)
    dst[lane + 64 * j] = pack4_q(v[j].x, v[j].y, v[j].z, v[j].w, scale, -128.f, 127.f);
  if (lane == 0) rowscale[row] = clipped / 127.0f;  // == 1/scale to 2^-24
}

// ---------------- 128x128x64 int8 MFMA GEMM, triple-buffer, 3 blocks/CU ---
// R13 showed 2 co-resident blocks run LOCKSTEP (no phase overlap). This
// round: 2048 SMALLER blocks (128x128, 4 waves 2x2, acc[4][4]=64 AGPR) at
// 3 blocks/CU -> 2048/256/3 ~ 2.67 launch rounds per CU: block finish times
// DESYNCHRONIZE after round 1, so one block's epilogue (VMEM) naturally
// coexists with neighbors' K-loops (MFMA) — the stagger R13's geometry
// couldn't produce. launch_bounds(256,3): cap 170 regs/wave (need ~90 VGPR
// + 64 AGPR). Spill sentinel: WRITE_SIZE.
// Sync = R14-verified triple-buffer counted-vmcnt, re-derived: STAGE issues
// 4/thread (2 A-rounds + 2 B-rounds) -> WAITBAR(4) (outstanding 8, retire
// to 4); 1 barrier/K-tile. LDS 3x16=48 KB/block (3x48=144<=160).
// Swizzle: 0-conflict BK=64 form, round-invariant (rows advance by 64).
// XCD remap: 2048 = 8*256, n-fastest (Wq 4MB fully L2-resident per XCD).
__global__ __launch_bounds__(256, 3) void gemm_kernel(
    const char* __restrict__ Eq, const char* __restrict__ Wq,
    const float* __restrict__ h, const float* __restrict__ bo,
    const float* __restrict__ a_eff, const float* __restrict__ rowscale,
    const float* __restrict__ scalf, float* __restrict__ out,
    int M, int N, int K) {
  __shared__ __attribute__((aligned(16))) char As[3][128 * 64];   // 3 x 8 KB
  __shared__ __attribute__((aligned(16))) char Bs[3][128 * 64];   // 3 x 8 KB

  int tid = threadIdx.x;
  int lane = tid & 63;
  int wave = tid >> 6;
  int wm = wave >> 1, wn = wave & 1;   // 2M x 2N wave grid

  // T1: XCD-aware bijective remap. grid = 2048 = 8 XCD * 256 tiles.
  int bid = blockIdx.x;
  int wgid = (bid & 7) * 256 + (bid >> 3);
  int n0 = (wgid & 15) * 128;    // 16 n-panels, n-fastest
  int m0 = (wgid >> 4) * 128;    // 128 m-panels

  // staging: A and B each 512 chunks (128 rows x 4), 2 rounds each.
  // thread t, round r: row=(t>>2)+64r, cc=t&3. lds linear; global source
  // inverse-swizzled: gcc = cc ^ ((row>>1)&3) (round-invariant: rows
  // advance by 64 -> (row>>1)&3 unchanged).
  int srow = tid >> 2;
  int gcc = (tid & 3) ^ ((srow >> 1) & 3);

  const char* ga = Eq + (size_t)(m0 + srow) * K + gcc * 16;
  const char* gb = Wq + (size_t)(n0 + srow) * K + gcc * 16;

  i32x4 acc[4][4] = {};

  int lm = lane & 15;
  int kg = lane >> 4;            // 4 K-groups of 16B = one 64-elem MFMA step
  int xr = (lm >> 1) & 3;        // read-side swizzle: (row>>1)&3 == (lm>>1)&3
  int arow_off = (wm * 64 + lm) * 64;
  int brow_off = (wn * 64 + lm) * 64;
  int ccA = (kg ^ xr) * 16;

#define STAGE(b)                                                    \
  do {                                                              \
    char* la_ = As[b] + tid * 16;                                   \
    char* lb_ = Bs[b] + tid * 16;                                   \
    _Pragma("unroll") for (int r_ = 0; r_ < 2; ++r_)                \
      async_copy16(ga + (size_t)(64 * r_) * K, la_ + 4096 * r_);    \
    _Pragma("unroll") for (int r_ = 0; r_ < 2; ++r_)                \
      async_copy16(gb + (size_t)(64 * r_) * K, lb_ + 4096 * r_);    \
    ga += 64; gb += 64;                                             \
  } while (0)

#define COMPUTE(b)                                                            \
  do {                                                                        \
    const char* arow_ = As[b] + arow_off;                                     \
    const char* brow_ = Bs[b] + brow_off;                                     \
    i32x4 af[4], bg[4];                                                       \
    _Pragma("unroll") for (int i = 0; i < 4; ++i)                             \
      af[i] = *(const i32x4*)(arow_ + i * 16 * 64 + ccA);                     \
    _Pragma("unroll") for (int j = 0; j < 4; ++j)                             \
      bg[j] = *(const i32x4*)(brow_ + j * 16 * 64 + ccA);                     \
    _Pragma("unroll") for (int i = 0; i < 4; ++i)                             \
      _Pragma("unroll") for (int j = 0; j < 4; ++j)                           \
        acc[i][j] =                                                           \
            __builtin_amdgcn_mfma_i32_16x16x64_i8(af[i], bg[j], acc[i][j],    \
                                                  0, 0, 0);                   \
  } while (0)

// counted wait: retire down to N outstanding VMEM ops, then raw barrier.
// sched_barrier(0) on both sides pins code motion across the sync point.
#define WAITBAR(N)                                                  \
  do {                                                              \
    __builtin_amdgcn_sched_barrier(0);                              \
    asm volatile("s_waitcnt vmcnt(" #N ")" ::: "memory");           \
    __builtin_amdgcn_s_barrier();                                   \
    __builtin_amdgcn_sched_barrier(0);                              \
  } while (0)

  // prologue: tile 0 -> buf0, tile 1 -> buf1 (8 loads in flight)
  STAGE(0);
  STAGE(1);

  // steady state: iter t = {WAITBAR(4); COMPUTE(t%3); STAGE(tile t+2 ->
  // buf (t+2)%3)}. Buf (t+2)%3 == (t-1)%3: its readers finished before
  // iter t's barrier -> no read-fence needed. Groups of 3 for static
  // indices; 10 groups cover tiles 0..29, staging through tile 31.
  for (int g = 0; g < 10; ++g) {
    WAITBAR(4); COMPUTE(0); STAGE(2);
    WAITBAR(4); COMPUTE(1); STAGE(0);
    WAITBAR(4); COMPUTE(2); STAGE(1);
  }
  // tail: tiles 30 (buf0) and 31 (buf1), 8 outstanding
  WAITBAR(4);
  COMPUTE(0);
  WAITBAR(0);       // drain last tile's loads
  COMPUTE(1);

  // ---- epilogue: scalar form, plain loads + NT stores (R10/R11 best) ----
  // C/D layout col=lane&15 (n), row=(lane>>4)*4+reg  [m89/m91]
  float mw = scalf[2];
  int r4 = (lane >> 4) * 4;
  float aeffj[4];
#pragma unroll
  for (int j = 0; j < 4; ++j) aeffj[j] = a_eff[n0 + wn * 64 + j * 16 + lm];
#pragma unroll
  for (int i = 0; i < 4; ++i) {
    int mb = m0 + wm * 64 + i * 16 + r4;
#pragma unroll
    for (int r = 0; r < 4; ++r) {
      size_t ro = (size_t)(mb + r) * N;
      float sm = rowscale[mb + r] * mw;
#pragma unroll
      for (int j = 0; j < 4; ++j) {
        int n = n0 + wn * 64 + j * 16 + lm;
        float hv = h[ro + n];
        float bv = bo[ro + n];
        float val = fmaf((float)acc[i][j][r], sm, fmaf(aeffj[j], hv, bv));
        __builtin_nontemporal_store(val, &out[ro + n]);
      }
    }
  }
#undef STAGE
#undef COMPUTE
#undef WAITBAR
}

extern "C" void kernel_launch(void* const* d_in, const int* in_sizes, int n_in,
                              void* d_out, int out_size, void* d_ws, size_t ws_size,
                              hipStream_t stream) {
  const float* h_p   = (const float*)d_in[0];
  const float* e_p   = (const float*)d_in[1];
  const float* bo_p  = (const float*)d_in[2];
  const float* A_raw = (const float*)d_in[3];
  const float* W_p   = (const float*)d_in[4];
  float* out = (float*)d_out;

  int D = in_sizes[3];        // 2048
  int M = in_sizes[0] / D;    // 16384
  int N = D, K = D;

  char* ws = (char*)d_ws;
  float* scalf     = (float*)ws;                       // [0..1]=dbl sum, [2]=mw, [3]=sw
  float* a_eff     = (float*)(ws + 4096);              // D floats
  float* rowscale  = (float*)(ws + 65536);             // M floats (64 KB)
  char* Wq         = ws + 131072;                      // N*K int8 codes (4 MB)
  char* Eq         = ws + 131072 + (size_t)N * K;      // M*K int8 codes (32 MB)

  hipMemsetAsync(d_ws, 0, 64, stream);
  int nW = N * K;
  abssum_kernel<<<256, 256, 0, stream>>>((const float4*)W_p, (double*)scalf, nW / 4);
  finalize_kernel<<<(D + 255) / 256, 256, 0, stream>>>(A_raw, scalf, a_eff, D,
                                                       1.0 / (double)nW);
  quantw_kernel<<<(nW / 4 + 1023) / 1024, 256, 0, stream>>>((const float4*)W_p,
                                                            (unsigned*)Wq, scalf, nW / 4);
  quante_kernel<<<M / 4, 256, 0, stream>>>(e_p, Eq, rowscale, K);
  int nwg = (N / 128) * (M / 128);   // 2048, %8 == 0 -> bijective XCD swizzle
  gemm_kernel<<<nwg, 256, 0, stream>>>(Eq, Wq, h_p, bo_p, a_eff, rowscale, scalf, out,
                                       M, N, K);
}

// Round 16
// 455.302 us; speedup vs baseline: 1.0571x; 1.0571x over previous
//
#include <hip/hip_runtime.h>
#include <stdint.h>

typedef __attribute__((ext_vector_type(4))) int i32x4;
typedef __attribute__((ext_vector_type(4))) float f32x4v;

#define EPSQ 1e-5f

__device__ __forceinline__ void async_copy16(const void* g, void* l) {
  __builtin_amdgcn_global_load_lds(
      (const __attribute__((address_space(1))) unsigned int*)g,
      (__attribute__((address_space(3))) unsigned int*)l,
      16, 0, 0);
}

// quantize 4 floats -> 4 packed int8 codes (two's complement)
__device__ __forceinline__ unsigned pack4_q(float x, float y, float z, float w,
                                            float scale, float lo, float hi) {
  int q0 = (int)fminf(fmaxf(rintf(x * scale), lo), hi);
  int q1 = (int)fminf(fmaxf(rintf(y * scale), lo), hi);
  int q2 = (int)fminf(fmaxf(rintf(z * scale), lo), hi);
  int q3 = (int)fminf(fmaxf(rintf(w * scale), lo), hi);
  return (unsigned)(q0 & 255) | ((unsigned)(q1 & 255) << 8) |
         ((unsigned)(q2 & 255) << 16) | ((unsigned)(q3 & 255) << 24);
}

// ---------------- W absmean reduction (double accumulation) ----------------
__global__ __launch_bounds__(256) void abssum_kernel(const float4* __restrict__ W,
                                                     double* __restrict__ sum, int n4) {
  __shared__ double red[4];
  double acc = 0.0;
  int stride = gridDim.x * blockDim.x;
  for (int v = blockIdx.x * blockDim.x + threadIdx.x; v < n4; v += stride) {
    float4 p = W[v];
    acc += (double)fabsf(p.x) + (double)fabsf(p.y) +
           (double)fabsf(p.z) + (double)fabsf(p.w);
  }
  for (int off = 32; off > 0; off >>= 1) acc += __shfl_down(acc, off);
  if ((threadIdx.x & 63) == 0) red[threadIdx.x >> 6] = acc;
  __syncthreads();
  if (threadIdx.x == 0)
    atomicAdd(sum, (red[0] + red[1]) + (red[2] + red[3]));
}

// ---------------- finalize scalars + A_eff ----------------
// scalf layout: [0..1]=double sum|W|, [2]=mw (dequant), [3]=sw=1/mw (quant)
__global__ void finalize_kernel(const float* __restrict__ A_raw, float* __restrict__ scalf,
                                float* __restrict__ a_eff, int D, double inv_cnt) {
  int i = blockIdx.x * blockDim.x + threadIdx.x;
  if (i < D) a_eff[i] = 0.99f * tanhf(A_raw[i]);
  if (i == 0) {
    double s = *(const double*)scalf;
    float mw = fmaxf((float)(s * inv_cnt), EPSQ);  // clip(mean|W|, EPS)
    scalf[2] = mw;
    scalf[3] = 1.0f / mw;
  }
}

// ---------------- ternary quantize W -> int8 codes {-1,0,1} ----------------
__global__ __launch_bounds__(256) void quantw_kernel(const float4* __restrict__ W,
                                                     unsigned* __restrict__ Wq,
                                                     const float* __restrict__ scalf, int n4) {
  float sw = scalf[3];
  int base = blockIdx.x * 1024 + threadIdx.x;
#pragma unroll
  for (int j = 0; j < 4; ++j) {
    int idx = base + 256 * j;
    if (idx < n4) {
      float4 p = W[idx];
      Wq[idx] = pack4_q(p.x, p.y, p.z, p.w, sw, -1.f, 1.f);
    }
  }
}

// ---------------- per-token int8 quant of e -> int8 codes [-127,127] -------
__global__ __launch_bounds__(256) void quante_kernel(const float* __restrict__ E,
                                                     char* __restrict__ Eq,
                                                     float* __restrict__ rowscale, int K) {
  int wave = threadIdx.x >> 6;
  int lane = threadIdx.x & 63;
  int row = blockIdx.x * 4 + wave;
  const float4* src = (const float4*)(E + (size_t)row * K);
  float4 v[8];  // K=2048: 512 float4/row = 64 lanes x 8
#pragma unroll
  for (int j = 0; j < 8; ++j) v[j] = src[lane + 64 * j];
  float amax = 0.f;
#pragma unroll
  for (int j = 0; j < 8; ++j)
    amax = fmaxf(amax, fmaxf(fmaxf(fabsf(v[j].x), fabsf(v[j].y)),
                             fmaxf(fabsf(v[j].z), fabsf(v[j].w))));
#pragma unroll
  for (int off = 32; off > 0; off >>= 1) amax = fmaxf(amax, __shfl_xor(amax, off));
  float clipped = fmaxf(amax, EPSQ);
  float scale = 127.0f / clipped;  // matches jax: 127/clip(max|x|,EPS)
  unsigned* dst = (unsigned*)(Eq + (size_t)row * K);
#pragma unroll
  for (int j = 0; j < 8; ++j)
    dst[lane + 64 * j] = pack4_q(v[j].x, v[j].y, v[j].z, v[j].w, scale, -128.f, 127.f);
  if (lane == 0) rowscale[row] = clipped / 127.0f;  // == 1/scale to 2^-24
}

// ------- 128x256x64 int8 MFMA GEMM, triple-buffer + LDS-transposed epilogue
// K-loop = R14 verified (best: 144.5us). NEW: after the K-loop the 72 KB
// staging LDS is dead -> repurpose it as a float[64][260] tile image
// (padding 260: 2-way banks = free, m136) to TRANSPOSE the epilogue:
//   W: scalar ds_write of acc*rowscale*mw fragments (row-scale applied here)
//   R: wave-per-row ds_read_b128 + CONTIGUOUS float4 h/bo loads + float4
//      NT out stores -> every VMEM instr covers 1 KB (was 4B scattered,
//      384 instrs/thread -> 96). Two 64-row halves (66.5 KB <= 73728).
// R9's transpose failed on 16B SCATTERED stores (WRITE +24%); this one's
// stores are full-line contiguous. Rounding: acc*sm rounds before adds
// (~1e-7 rel, invisible under 2^-5 quant noise).
__global__ __launch_bounds__(256, 2) void gemm_kernel(
    const char* __restrict__ Eq, const char* __restrict__ Wq,
    const float* __restrict__ h, const float* __restrict__ bo,
    const float* __restrict__ a_eff, const float* __restrict__ rowscale,
    const float* __restrict__ scalf, float* __restrict__ out,
    int M, int N, int K) {
  __shared__ __attribute__((aligned(16))) char smem[73728];
#define AS(b) (smem + (b) * 8192)            // 3 x 8 KB  A buffers
#define BS(b) (smem + 24576 + (b) * 16384)   // 3 x 16 KB B buffers

  int tid = threadIdx.x;
  int lane = tid & 63;
  int wave = tid >> 6;
  int wn = wave & 3;             // 1M x 4N wave grid

  // T1: XCD-aware bijective remap. grid = 1024 = 8 XCD * 128 tiles.
  int bid = blockIdx.x;
  int wgid = (bid & 7) * 128 + (bid >> 3);
  int n0 = (wgid & 7) * 256;     // 8 n-panels, n-fastest
  int m0 = (wgid >> 3) * 128;    // 128 m-panels

  // staging: A = 512 chunks (128 rows x 4), 2 rounds; B = 1024 chunks
  // (256 rows x 4), 4 rounds. thread t, round r: row=(t>>2)+64r, cc=t&3.
  // lds linear; global source inverse-swizzled: gcc = cc ^ ((row>>1)&3)
  // (round-invariant: rows advance by 64 -> (row>>1)&3 unchanged).
  int srow = tid >> 2;
  int gcc = (tid & 3) ^ ((srow >> 1) & 3);

  const char* ga = Eq + (size_t)(m0 + srow) * K + gcc * 16;
  const char* gb = Wq + (size_t)(n0 + srow) * K + gcc * 16;

  i32x4 acc[8][4] = {};

  int lm = lane & 15;
  int kg = lane >> 4;            // 4 K-groups of 16B = one 64-elem MFMA step
  int xr = (lm >> 1) & 3;        // read-side swizzle: (row>>1)&3 == (lm>>1)&3
  int arow_off = lm * 64;        // wm == 0 (waves split N only)
  int brow_off = (wn * 64 + lm) * 64;
  int ccA = (kg ^ xr) * 16;

#define STAGE(b)                                                    \
  do {                                                              \
    char* la_ = AS(b) + tid * 16;                                   \
    char* lb_ = BS(b) + tid * 16;                                   \
    _Pragma("unroll") for (int r_ = 0; r_ < 2; ++r_)                \
      async_copy16(ga + (size_t)(64 * r_) * K, la_ + 4096 * r_);    \
    _Pragma("unroll") for (int r_ = 0; r_ < 4; ++r_)                \
      async_copy16(gb + (size_t)(64 * r_) * K, lb_ + 4096 * r_);    \
    ga += 64; gb += 64;                                             \
  } while (0)

#define COMPUTE(b)                                                            \
  do {                                                                        \
    const char* arow_ = AS(b) + arow_off;                                     \
    const char* brow_ = BS(b) + brow_off;                                     \
    i32x4 af[8], bg[4];                                                       \
    _Pragma("unroll") for (int i = 0; i < 8; ++i)                             \
      af[i] = *(const i32x4*)(arow_ + i * 16 * 64 + ccA);                     \
    _Pragma("unroll") for (int j = 0; j < 4; ++j)                             \
      bg[j] = *(const i32x4*)(brow_ + j * 16 * 64 + ccA);                     \
    _Pragma("unroll") for (int i = 0; i < 8; ++i)                             \
      _Pragma("unroll") for (int j = 0; j < 4; ++j)                           \
        acc[i][j] =                                                           \
            __builtin_amdgcn_mfma_i32_16x16x64_i8(af[i], bg[j], acc[i][j],    \
                                                  0, 0, 0);                   \
  } while (0)

// counted wait: retire down to N outstanding VMEM ops, then raw barrier.
#define WAITBAR(N)                                                  \
  do {                                                              \
    __builtin_amdgcn_sched_barrier(0);                              \
    asm volatile("s_waitcnt vmcnt(" #N ")" ::: "memory");           \
    __builtin_amdgcn_s_barrier();                                   \
    __builtin_amdgcn_sched_barrier(0);                              \
  } while (0)

  // prologue: tile 0 -> buf0, tile 1 -> buf1 (12 loads in flight)
  STAGE(0);
  STAGE(1);

  // steady state: iter t = {WAITBAR(6); COMPUTE(t%3); STAGE(tile t+2 ->
  // buf (t+2)%3)}. Groups of 3 for static indices; tiles 0..29, staging
  // through 31. (R14-verified.)
  for (int g = 0; g < 10; ++g) {
    WAITBAR(6); COMPUTE(0); STAGE(2);
    WAITBAR(6); COMPUTE(1); STAGE(0);
    WAITBAR(6); COMPUTE(2); STAGE(1);
  }
  // tail: tiles 30 (buf0) and 31 (buf1), 12 outstanding
  WAITBAR(6);
  COMPUTE(0);
  WAITBAR(0);       // drain last tile's loads
  COMPUTE(1);

  // ---- LDS-transposed epilogue ----
  // C/D layout col=lane&15 (n), row=(lane>>4)*4+reg [m89/m91].
  // Two halves of 64 rows each; LDS image float[64][260] (padded).
  float* C_lds = (float*)smem;
  float mw = scalf[2];
  int r4 = (lane >> 4) * 4;
  int colg = n0 + lane * 4;                       // this thread's 4 cols (R)
  f32x4v aeff4 = *(const f32x4v*)&a_eff[colg];    // col-fixed across strips

#pragma unroll
  for (int hf = 0; hf < 2; ++hf) {
    __syncthreads();   // all waves past K-loop LDS reads (hf=0) / R-phase (hf=1)
    // W: scalar ds_write of scaled fragments. Banks: lanes 16a+b ->
    // (a*1040 + b) % 32 = 2-way (free, m136).
#pragma unroll
    for (int il = 0; il < 4; ++il) {
      int i = hf * 4 + il;
      int rl0 = il * 16 + r4;                     // local row base 0..63
#pragma unroll
      for (int r = 0; r < 4; ++r) {
        float sm = rowscale[m0 + hf * 64 + rl0 + r] * mw;
#pragma unroll
        for (int j = 0; j < 4; ++j) {
          int col = wn * 64 + j * 16 + lm;
          C_lds[(rl0 + r) * 260 + col] = (float)acc[i][j][r] * sm;
        }
      }
    }
    __syncthreads();
    // R: wave w handles rows strip*4 + w; lanes cover 256 cols as float4
    // -> ds_read_b128 lane-contiguous (conflict-free) + 1KB-contiguous
    // global h/bo loads and NT out stores.
#pragma unroll
    for (int s = 0; s < 16; ++s) {
      int rl = s * 4 + wave;
      f32x4v c4 = *(const f32x4v*)&C_lds[rl * 260 + lane * 4];
      size_t ro = (size_t)(m0 + hf * 64 + rl) * N + colg;
      f32x4v h4 = *(const f32x4v*)&h[ro];
      f32x4v b4 = *(const f32x4v*)&bo[ro];
      f32x4v o4;
      o4.x = fmaf(aeff4.x, h4.x, b4.x) + c4.x;
      o4.y = fmaf(aeff4.y, h4.y, b4.y) + c4.y;
      o4.z = fmaf(aeff4.z, h4.z, b4.z) + c4.z;
      o4.w = fmaf(aeff4.w, h4.w, b4.w) + c4.w;
      __builtin_nontemporal_store(o4, (f32x4v*)&out[ro]);
    }
  }
#undef STAGE
#undef COMPUTE
#undef WAITBAR
#undef AS
#undef BS
}

extern "C" void kernel_launch(void* const* d_in, const int* in_sizes, int n_in,
                              void* d_out, int out_size, void* d_ws, size_t ws_size,
                              hipStream_t stream) {
  const float* h_p   = (const float*)d_in[0];
  const float* e_p   = (const float*)d_in[1];
  const float* bo_p  = (const float*)d_in[2];
  const float* A_raw = (const float*)d_in[3];
  const float* W_p   = (const float*)d_in[4];
  float* out = (float*)d_out;

  int D = in_sizes[3];        // 2048
  int M = in_sizes[0] / D;    // 16384
  int N = D, K = D;

  char* ws = (char*)d_ws;
  float* scalf     = (float*)ws;                       // [0..1]=dbl sum, [2]=mw, [3]=sw
  float* a_eff     = (float*)(ws + 4096);              // D floats
  float* rowscale  = (float*)(ws + 65536);             // M floats (64 KB)
  char* Wq         = ws + 131072;                      // N*K int8 codes (4 MB)
  char* Eq         = ws + 131072 + (size_t)N * K;      // M*K int8 codes (32 MB)

  hipMemsetAsync(d_ws, 0, 64, stream);
  int nW = N * K;
  abssum_kernel<<<256, 256, 0, stream>>>((const float4*)W_p, (double*)scalf, nW / 4);
  finalize_kernel<<<(D + 255) / 256, 256, 0, stream>>>(A_raw, scalf, a_eff, D,
                                                       1.0 / (double)nW);
  quantw_kernel<<<(nW / 4 + 1023) / 1024, 256, 0, stream>>>((const float4*)W_p,
                                                            (unsigned*)Wq, scalf, nW / 4);
  quante_kernel<<<M / 4, 256, 0, stream>>>(e_p, Eq, rowscale, K);
  int nwg = (N / 256) * (M / 128);   // 1024, %8 == 0 -> bijective XCD swizzle
  gemm_kernel<<<nwg, 256, 0, stream>>>(Eq, Wq, h_p, bo_p, a_eff, rowscale, scalf, out,
                                       M, N, K);
}